// Round 11
// baseline (146.459 us; speedup 1.0000x reference)
//
#include <hip/hip_runtime.h>
#include <hip/hip_bf16.h>

#define B_SZ 2
#define T_SEQ 1024
#define D_MODEL 1024
#define N_HEADS 16
#define TREE_DEPTH 5
#define DH 64

typedef __attribute__((ext_vector_type(8))) short short8;
typedef __attribute__((ext_vector_type(4))) float f32x4;

__device__ __forceinline__ ushort f2bf(float f) {
    uint32_t u = __float_as_uint(f);
    u += 0x7FFFu + ((u >> 16) & 1u);
    return (ushort)(u >> 16);
}

// async global->LDS 16B/lane; dest = wave-uniform base + lane*16
__device__ __forceinline__ void gll16(const void* g, void* l) {
    __builtin_amdgcn_global_load_lds(
        (const __attribute__((address_space(1))) void*)g,
        (__attribute__((address_space(3))) void*)l, 16, 0, 0);
}

// ---------------------------------------------------------------------------
// Fused prologue: [0,1024) convert x->xb ; [1024,3072) transpose Wv/Wo ;
// [3072,3088) transpose Wp.   (R10-identical)
// ---------------------------------------------------------------------------
__global__ __launch_bounds__(256) void prologue(
    const float* __restrict__ x, const float* __restrict__ Wv,
    const float* __restrict__ Wo, const float* __restrict__ Wp,
    ushort* __restrict__ xb, ushort* __restrict__ Wvt,
    ushort* __restrict__ Wot, ushort* __restrict__ Wpt)
{
    __shared__ __align__(16) char sm[20480];
    const int bid = blockIdx.x, tid = threadIdx.x;
    if (bid < 1024) {
        const int i = (bid * 256 + tid) * 8;
        const float4 a = *(const float4*)(x + i);
        const float4 b = *(const float4*)(x + i + 4);
        ushort o[8] = {f2bf(a.x), f2bf(a.y), f2bf(a.z), f2bf(a.w),
                       f2bf(b.x), f2bf(b.y), f2bf(b.z), f2bf(b.w)};
        *(uint4*)(xb + i) = *(const uint4*)o;
    } else if (bid < 3072) {
        const int t = bid - 1024;
        const float* W = (t < 1024) ? Wv : Wo;
        ushort* Wt = (t < 1024) ? Wvt : Wot;
        const int ti = t & 1023;
        const int n0 = (ti & 31) * 32, k0 = (ti >> 5) * 32;
        float (*tile)[33] = (float(*)[33])sm;
        const int tx = tid & 31, ty = tid >> 5;
        #pragma unroll
        for (int i = 0; i < 4; ++i)
            tile[ty + i * 8][tx] = W[(size_t)(k0 + ty + i * 8) * 1024 + n0 + tx];
        __syncthreads();
        #pragma unroll
        for (int i = 0; i < 4; ++i)
            Wt[(size_t)(n0 + ty + i * 8) * 1024 + k0 + tx] = f2bf(tile[tx][ty + i * 8]);
    } else {
        float* tile = (float*)sm;            // 64*80
        const int k0 = (bid - 3072) * 64;
        #pragma unroll
        for (int j = 0; j < 20; ++j) {
            const int i = tid + j * 256;     // i = k*80 + n
            tile[i] = Wp[(size_t)k0 * 80 + i];
        }
        __syncthreads();
        #pragma unroll
        for (int j = 0; j < 20; ++j) {
            const int o = tid + j * 256;     // o = n*64 + k
            const int n = o >> 6, k = o & 63;
            Wpt[(size_t)n * 1024 + k0 + k] = f2bf(tile[k * 80 + n]);
        }
    }
}

// ---------------------------------------------------------------------------
// bf16 MFMA GEMM body: C(MxN) = A(MxK) @ Bt(NxK)^T. BM=64 BN=128 BK=64,
// 4 waves (2 m-strips x 2 n-strips; wave tile 32m x 64n). Both operands via
// double-buffered gll16 (A: 2/wave/iter, B: 4/wave/iter), 1 barrier/iter,
// 16 MFMA per wave per iter (vs 8 at BN=64 — better staging amortization).
// LDS: As 2x8KB + Bs 2x16KB = 48 KB -> 3 blocks/CU.
// ---------------------------------------------------------------------------
template <bool OUT_BF16>
__device__ __forceinline__ void gemm_body(
    const ushort* __restrict__ A, const ushort* __restrict__ Bt,
    void* __restrict__ Cv, int N, int K, int bx, int by,
    ushort* As, ushort* Bs)
{
    const int tid = threadIdx.x;
    const int lane = tid & 63;
    const int w = tid >> 6;
    const int wm = w & 1, wn = w >> 1;
    const int rowBase = by * 64;
    const int colBase = bx * 128;

    const int srow = lane & 15;
    const int sk = (lane >> 4) * 8;

    const ushort* gA  = A + (size_t)(rowBase + w * 16 + srow) * K + sk;
    const ushort* gB0 = Bt + (size_t)(colBase + (w * 2 + 0) * 16 + srow) * K + sk;
    const ushort* gB1 = Bt + (size_t)(colBase + (w * 2 + 1) * 16 + srow) * K + sk;

    f32x4 acc[2][4];
    #pragma unroll
    for (int i = 0; i < 2; ++i)
        #pragma unroll
        for (int j = 0; j < 4; ++j) acc[i][j] = (f32x4)0.0f;

    // preload tile 0
    gll16(gA,       As + (w * 2 + 0) * 512);
    gll16(gA + 32,  As + (w * 2 + 1) * 512);
    gll16(gB0,      Bs + ((w * 2 + 0) * 2 + 0) * 512);
    gll16(gB0 + 32, Bs + ((w * 2 + 0) * 2 + 1) * 512);
    gll16(gB1,      Bs + ((w * 2 + 1) * 2 + 0) * 512);
    gll16(gB1 + 32, Bs + ((w * 2 + 1) * 2 + 1) * 512);

    const int niter = K / 64;
    for (int it = 0; it < niter; ++it) {
        __syncthreads();
        const int curA = (it & 1) * 4096;
        const int curB = (it & 1) * 8192;
        if (it + 1 < niter) {
            const int nxtA = ((it + 1) & 1) * 4096;
            const int nxtB = ((it + 1) & 1) * 8192;
            const int ko = (it + 1) * 64;
            gll16(gA + ko,       As + nxtA + (w * 2 + 0) * 512);
            gll16(gA + ko + 32,  As + nxtA + (w * 2 + 1) * 512);
            gll16(gB0 + ko,      Bs + nxtB + ((w * 2 + 0) * 2 + 0) * 512);
            gll16(gB0 + ko + 32, Bs + nxtB + ((w * 2 + 0) * 2 + 1) * 512);
            gll16(gB1 + ko,      Bs + nxtB + ((w * 2 + 1) * 2 + 0) * 512);
            gll16(gB1 + ko + 32, Bs + nxtB + ((w * 2 + 1) * 2 + 1) * 512);
        }
        #pragma unroll
        for (int ks = 0; ks < 2; ++ks) {
            short8 af[2], bf[4];
            #pragma unroll
            for (int i = 0; i < 2; ++i)
                af[i] = *(const short8*)(As + curA + ((wm * 2 + i) * 2 + ks) * 512 + lane * 8);
            #pragma unroll
            for (int j = 0; j < 4; ++j)
                bf[j] = *(const short8*)(Bs + curB + ((wn * 4 + j) * 2 + ks) * 512 + lane * 8);
            #pragma unroll
            for (int i = 0; i < 2; ++i)
                #pragma unroll
                for (int j = 0; j < 4; ++j)
                    acc[i][j] = __builtin_amdgcn_mfma_f32_16x16x32_bf16(
                        af[i], bf[j], acc[i][j], 0, 0, 0);
        }
    }

    const int quad = lane >> 4, m16 = lane & 15;
    #pragma unroll
    for (int i = 0; i < 2; ++i)
        #pragma unroll
        for (int j = 0; j < 4; ++j) {
            const int col = colBase + wn * 64 + j * 16 + m16;
            #pragma unroll
            for (int r = 0; r < 4; ++r) {
                const int row = rowBase + wm * 32 + i * 16 + quad * 4 + r;
                if (OUT_BF16)
                    ((ushort*)Cv)[(size_t)row * N + col] = f2bf(acc[i][j][r]);
                else
                    ((float*)Cv)[(size_t)row * N + col] = acc[i][j][r];
            }
        }
}

// ---------------------------------------------------------------------------
// paths+phi body (R10-identical)
// ---------------------------------------------------------------------------
__device__ __forceinline__ void phi_body(
    const ushort* __restrict__ xb, const ushort* __restrict__ Wpt,
    const float* __restrict__ bp, ushort* __restrict__ Phi,
    int blk, float* red, float* p_s)
{
    const int tid = threadIdx.x;
    const int lane = tid & 63, w = tid >> 6;
    const int quad = lane >> 4, m16 = lane & 15;
    const int row0 = blk * 16;

    f32x4 acc[5];
    #pragma unroll
    for (int nb = 0; nb < 5; ++nb) acc[nb] = (f32x4)0.0f;

    const ushort* ap = xb + (size_t)(row0 + m16) * 1024 + w * 256 + quad * 8;
    const ushort* bpz = Wpt + (size_t)m16 * 1024 + w * 256 + quad * 8;
    #pragma unroll
    for (int it = 0; it < 8; ++it) {
        const short8 af = *(const short8*)(ap + it * 32);
        #pragma unroll
        for (int nb = 0; nb < 5; ++nb) {
            const short8 bf = *(const short8*)(bpz + (size_t)nb * 16 * 1024 + it * 32);
            acc[nb] = __builtin_amdgcn_mfma_f32_16x16x32_bf16(af, bf, acc[nb], 0, 0, 0);
        }
    }
    #pragma unroll
    for (int nb = 0; nb < 5; ++nb)
        #pragma unroll
        for (int r = 0; r < 4; ++r)
            red[(w * 16 + quad * 4 + r) * 80 + nb * 16 + m16] = acc[nb][r];
    __syncthreads();
    #pragma unroll
    for (int j = 0; j < 5; ++j) {
        const int i = tid + j * 256;
        const int rr = i / 80, cc = i - rr * 80;
        const float v = red[(0 * 16 + rr) * 80 + cc] + red[(1 * 16 + rr) * 80 + cc] +
                        red[(2 * 16 + rr) * 80 + cc] + red[(3 * 16 + rr) * 80 + cc] + bp[cc];
        p_s[rr * 80 + cc] = 1.0f / (1.0f + __expf(-v));
    }
    __syncthreads();
    #pragma unroll
    for (int j = 0; j < 8; ++j) {
        const int c = tid + j * 256;
        const int rr = c >> 7, rem = c & 127;
        const int h = rem >> 3, f8 = (rem & 7) * 8;
        const float* pr = &p_s[rr * 80 + h * 5];
        ushort o[8];
        #pragma unroll
        for (int e = 0; e < 8; ++e) {
            const int f = f8 + e;
            float val = 0.0f;
            if (f < 62) {
                int d, off;
                if (f < 2)       { d = 1; off = 0; }
                else if (f < 6)  { d = 2; off = 2; }
                else if (f < 14) { d = 3; off = 6; }
                else if (f < 30) { d = 4; off = 14; }
                else             { d = 5; off = 30; }
                const int e2 = f - off;
                float prod = 1.0f;
                for (int jj = 1; jj <= d; ++jj) {
                    const float p = pr[jj - 1];
                    prod *= ((e2 >> (d - jj)) & 1) ? (1.0f - p) : p;
                }
                val = prod;
            }
            o[e] = f2bf(val);
        }
        const int grow = row0 + rr;
        const int b = grow >> 10, t = grow & 1023;
        *(uint4*)(Phi + ((size_t)(b * 16 + h) * 1024 + t) * 64 + f8) =
            *(const uint4*)o;
    }
}

// ---------------------------------------------------------------------------
// mid: blocks [0,128) = paths+phi FIRST (overlaps the GEMM),
//      blocks [128,384) = Vt GEMM (Wvt @ xb^T), 64x128 tiles.
// ---------------------------------------------------------------------------
__global__ __launch_bounds__(256) void mid_kernel(
    const ushort* __restrict__ xb, const ushort* __restrict__ Wvt,
    const ushort* __restrict__ Wpt, const float* __restrict__ bp,
    ushort* __restrict__ Vt, ushort* __restrict__ Phi)
{
    __shared__ __align__(16) char sm[49152];
    const int bid = blockIdx.x;
    if (bid < 128) {
        float* red = (float*)sm;             // 20480 B
        float* p_s = (float*)(sm + 20480);   // 5120 B
        phi_body(xb, Wpt, bp, Phi, bid, red, p_s);
    } else {
        const int g = bid - 128;             // 0..255
        ushort* As = (ushort*)sm;            // 2 x 4096 ushorts (16 KB)
        ushort* Bs = As + 8192;              // 2 x 8192 ushorts (32 KB)
        gemm_body<true>(Wvt, xb, Vt, 2048, 1024,
                        g & 15, g >> 4, As, Bs);
    }
}

// ---------------------------------------------------------------------------
// final GEMM: out = ctxb @ Wot^T  (fp32 out). grid (8, 32) = 256 blocks.
// ---------------------------------------------------------------------------
__global__ __launch_bounds__(256) void gemm_out(
    const ushort* __restrict__ ctxb, const ushort* __restrict__ Wot,
    float* __restrict__ out)
{
    __shared__ __align__(16) ushort sm[24576];   // As 2x4096 + Bs 2x8192
    gemm_body<false>(ctxb, Wot, out, 1024, 1024,
                     blockIdx.x, blockIdx.y, sm, sm + 8192);
}

// ---------------------------------------------------------------------------
// MFMA attention, S^T form (R10-identical).
// ---------------------------------------------------------------------------
__global__ __launch_bounds__(256) void attn_mfma(
    const ushort* __restrict__ Phi, const ushort* __restrict__ Vt,
    ushort* __restrict__ ctxb)
{
    const int qt = 15 - blockIdx.x;
    const int bh = blockIdx.y;
    const int b = bh >> 4, h = bh & 15;
    const int tid = threadIdx.x;
    const int lane = tid & 63;
    const int w = tid >> 6;
    const int quad = lane >> 4, m16 = lane & 15;

    __shared__ __align__(16) ushort K_s[2][4096];
    __shared__ __align__(16) ushort V_s[2][4096];
    __shared__ __align__(16) ushort W_s[4096];
    __shared__ float den_s[4][16];

    const int srow = lane & 15;
    const int sk = (lane >> 4) * 8;
    const ushort* gK = Phi + (size_t)bh * 1024 * 64 + (w * 16 + srow) * 64 + sk;
    const ushort* gV = Vt + (size_t)(h * 64 + w * 16 + srow) * 2048 + b * 1024 + sk;

    const int qglob = qt * 64 + w * 16 + m16;
    const ushort* qbase = Phi + ((size_t)bh * 1024 + qglob) * 64 + quad * 8;
    const short8 qf0 = *(const short8*)qbase;
    const short8 qf1 = *(const short8*)(qbase + 32);

    f32x4 cacc[4];
    #pragma unroll
    for (int nb = 0; nb < 4; ++nb) cacc[nb] = (f32x4)0.0f;
    float den = 0.0f;

    gll16(gK,      K_s[0] + (w * 2 + 0) * 512);
    gll16(gK + 32, K_s[0] + (w * 2 + 1) * 512);
    gll16(gV,      V_s[0] + (w * 2 + 0) * 512);
    gll16(gV + 32, V_s[0] + (w * 2 + 1) * 512);

    const float C = 0.28853901817f;   // 0.2 * log2(e)

    for (int kt = 0; kt <= qt; ++kt) {
        const int cur = kt & 1;
        __syncthreads();
        if (kt < qt) {
            const int nxt = cur ^ 1;
            const ushort* nK = gK + (kt + 1) * 4096;
            const ushort* nV = gV + (kt + 1) * 64;
            gll16(nK,      K_s[nxt] + (w * 2 + 0) * 512);
            gll16(nK + 32, K_s[nxt] + (w * 2 + 1) * 512);
            gll16(nV,      V_s[nxt] + (w * 2 + 0) * 512);
            gll16(nV + 32, V_s[nxt] + (w * 2 + 1) * 512);
        }
        const bool diag = (kt == qt);
        #pragma unroll
        for (int nb = 0; nb < 4; ++nb) {
            const short8 kf0 = *(const short8*)(K_s[cur] + (nb * 2 + 0) * 512 + lane * 8);
            const short8 kf1 = *(const short8*)(K_s[cur] + (nb * 2 + 1) * 512 + lane * 8);
            f32x4 s = (f32x4)0.0f;
            s = __builtin_amdgcn_mfma_f32_16x16x32_bf16(kf0, qf0, s, 0, 0, 0);
            s = __builtin_amdgcn_mfma_f32_16x16x32_bf16(kf1, qf1, s, 0, 0, 0);
            ushort o[4];
            if (diag) {
                const int k0g = kt * 64 + nb * 16 + quad * 4;
                #pragma unroll
                for (int r = 0; r < 4; ++r) {
                    float wgt = 0.0f;
                    if (k0g + r <= qglob) wgt = exp2f(s[r] * C);
                    den += wgt;
                    o[r] = f2bf(wgt);
                }
            } else {
                #pragma unroll
                for (int r = 0; r < 4; ++r) {
                    const float wgt = exp2f(s[r] * C);
                    den += wgt;
                    o[r] = f2bf(wgt);
                }
            }
            const int addr = (w * 2 + (nb >> 1)) * 512 +
                             ((nb & 1) * 2 + (quad >> 1)) * 128 +
                             m16 * 8 + (quad & 1) * 4;
            *(uint2*)(W_s + addr) = *(const uint2*)o;
        }
        const short8 wf0 = *(const short8*)(W_s + (w * 2 + 0) * 512 + lane * 8);
        const short8 wf1 = *(const short8*)(W_s + (w * 2 + 1) * 512 + lane * 8);
        #pragma unroll
        for (int nb = 0; nb < 4; ++nb) {
            const short8 vf0 = *(const short8*)(V_s[cur] + (nb * 2 + 0) * 512 + lane * 8);
            const short8 vf1 = *(const short8*)(V_s[cur] + (nb * 2 + 1) * 512 + lane * 8);
            cacc[nb] = __builtin_amdgcn_mfma_f32_16x16x32_bf16(wf0, vf0, cacc[nb], 0, 0, 0);
            cacc[nb] = __builtin_amdgcn_mfma_f32_16x16x32_bf16(wf1, vf1, cacc[nb], 0, 0, 0);
        }
    }

    den += __shfl_xor(den, 16);
    den += __shfl_xor(den, 32);
    den_s[w][m16] = den;
    __syncthreads();
    float inv[4];
    #pragma unroll
    for (int r = 0; r < 4; ++r) inv[r] = 1.0f / den_s[w][quad * 4 + r];

    #pragma unroll
    for (int nb = 0; nb < 4; ++nb) {
        const int dim = h * 64 + nb * 16 + m16;
        #pragma unroll
        for (int r = 0; r < 4; ++r) {
            const int token = qt * 64 + w * 16 + quad * 4 + r;
            ctxb[(size_t)(b * 1024 + token) * D_MODEL + dim] = f2bf(cacc[nb][r] * inv[r]);
        }
    }
}

// ---------------------------------------------------------------------------
extern "C" void kernel_launch(void* const* d_in, const int* in_sizes, int n_in,
                              void* d_out, int out_size, void* d_ws, size_t ws_size,
                              hipStream_t stream)
{
    const float* x  = (const float*)d_in[0];
    const float* Wp = (const float*)d_in[1];
    const float* bp = (const float*)d_in[2];
    const float* Wv = (const float*)d_in[3];
    const float* Wo = (const float*)d_in[4];
    float* out = (float*)d_out;

    char* ws = (char*)d_ws;
    ushort* xb   = (ushort*)(ws);                 // 4 MB
    ushort* Wvt  = (ushort*)(ws + (4u  << 20));   // 2 MB
    ushort* Wot  = (ushort*)(ws + (6u  << 20));   // 2 MB
    ushort* Phi  = (ushort*)(ws + (8u  << 20));   // 4 MB
    ushort* Vt   = (ushort*)(ws + (12u << 20));   // 4 MB
    ushort* ctxb = (ushort*)(ws + (16u << 20));   // 4 MB
    ushort* Wpt  = (ushort*)(ws + (20u << 20));   // 160 KB

    prologue<<<3088, 256, 0, stream>>>(x, Wv, Wo, Wp, xb, Wvt, Wot, Wpt);
    mid_kernel<<<384, 256, 0, stream>>>(xb, Wvt, Wpt, bp, Vt, Phi);
    attn_mfma<<<dim3(16, 32), 256, 0, stream>>>(Phi, Vt, ctxb);
    gemm_out<<<dim3(8, 32), 256, 0, stream>>>(ctxb, Wot, out);
}

// Round 12
// 141.974 us; speedup vs baseline: 1.0316x; 1.0316x over previous
//
#include <hip/hip_runtime.h>
#include <hip/hip_bf16.h>

#define B_SZ 2
#define T_SEQ 1024
#define D_MODEL 1024
#define N_HEADS 16
#define TREE_DEPTH 5
#define DH 64

typedef __attribute__((ext_vector_type(8))) short short8;
typedef __attribute__((ext_vector_type(4))) float f32x4;

__device__ __forceinline__ ushort f2bf(float f) {
    uint32_t u = __float_as_uint(f);
    u += 0x7FFFu + ((u >> 16) & 1u);
    return (ushort)(u >> 16);
}

// async global->LDS 16B/lane; dest = wave-uniform base + lane*16
__device__ __forceinline__ void gll16(const void* g, void* l) {
    __builtin_amdgcn_global_load_lds(
        (const __attribute__((address_space(1))) void*)g,
        (__attribute__((address_space(3))) void*)l, 16, 0, 0);
}

// ---------------------------------------------------------------------------
// Fused prologue: [0,1024) convert x->xb ; [1024,3072) transpose Wv/Wo ;
// [3072,3088) transpose Wp.   (R10-identical)
// ---------------------------------------------------------------------------
__global__ __launch_bounds__(256) void prologue(
    const float* __restrict__ x, const float* __restrict__ Wv,
    const float* __restrict__ Wo, const float* __restrict__ Wp,
    ushort* __restrict__ xb, ushort* __restrict__ Wvt,
    ushort* __restrict__ Wot, ushort* __restrict__ Wpt)
{
    __shared__ __align__(16) char sm[20480];
    const int bid = blockIdx.x, tid = threadIdx.x;
    if (bid < 1024) {
        const int i = (bid * 256 + tid) * 8;
        const float4 a = *(const float4*)(x + i);
        const float4 b = *(const float4*)(x + i + 4);
        ushort o[8] = {f2bf(a.x), f2bf(a.y), f2bf(a.z), f2bf(a.w),
                       f2bf(b.x), f2bf(b.y), f2bf(b.z), f2bf(b.w)};
        *(uint4*)(xb + i) = *(const uint4*)o;
    } else if (bid < 3072) {
        const int t = bid - 1024;
        const float* W = (t < 1024) ? Wv : Wo;
        ushort* Wt = (t < 1024) ? Wvt : Wot;
        const int ti = t & 1023;
        const int n0 = (ti & 31) * 32, k0 = (ti >> 5) * 32;
        float (*tile)[33] = (float(*)[33])sm;
        const int tx = tid & 31, ty = tid >> 5;
        #pragma unroll
        for (int i = 0; i < 4; ++i)
            tile[ty + i * 8][tx] = W[(size_t)(k0 + ty + i * 8) * 1024 + n0 + tx];
        __syncthreads();
        #pragma unroll
        for (int i = 0; i < 4; ++i)
            Wt[(size_t)(n0 + ty + i * 8) * 1024 + k0 + tx] = f2bf(tile[tx][ty + i * 8]);
    } else {
        float* tile = (float*)sm;            // 64*80
        const int k0 = (bid - 3072) * 64;
        #pragma unroll
        for (int j = 0; j < 20; ++j) {
            const int i = tid + j * 256;     // i = k*80 + n
            tile[i] = Wp[(size_t)k0 * 80 + i];
        }
        __syncthreads();
        #pragma unroll
        for (int j = 0; j < 20; ++j) {
            const int o = tid + j * 256;     // o = n*64 + k
            const int n = o >> 6, k = o & 63;
            Wpt[(size_t)n * 1024 + k0 + k] = f2bf(tile[k * 80 + n]);
        }
    }
}

// ---------------------------------------------------------------------------
// bf16 MFMA GEMM body (R10-identical): C(MxN) = A(MxK) @ Bt(NxK)^T.
// BM=64 BN=64 BK=64, 4 waves (2x2), both operands double-buffered gll16,
// 1 barrier/iter. 512 blocks = 2/CU for cross-block latency hiding.
// ---------------------------------------------------------------------------
template <bool OUT_BF16>
__device__ __forceinline__ void gemm_body(
    const ushort* __restrict__ A, const ushort* __restrict__ Bt,
    void* __restrict__ Cv, int N, int K, int bx, int by,
    ushort* As, ushort* Bs)
{
    const int tid = threadIdx.x;
    const int lane = tid & 63;
    const int w = tid >> 6;
    const int wm = w & 1, wn = w >> 1;
    const int rowBase = by * 64;
    const int colBase = bx * 64;

    const int srow = lane & 15;
    const int sk = (lane >> 4) * 8;

    const ushort* gA = A + (size_t)(rowBase + w * 16 + srow) * K + sk;
    const ushort* gB = Bt + (size_t)(colBase + w * 16 + srow) * K + sk;

    f32x4 acc[2][2];
    #pragma unroll
    for (int i = 0; i < 2; ++i) {
        acc[i][0] = (f32x4)0.0f;
        acc[i][1] = (f32x4)0.0f;
    }

    gll16(gA,      As + (w * 2 + 0) * 512);
    gll16(gA + 32, As + (w * 2 + 1) * 512);
    gll16(gB,      Bs + (w * 2 + 0) * 512);
    gll16(gB + 32, Bs + (w * 2 + 1) * 512);

    const int niter = K / 64;
    for (int it = 0; it < niter; ++it) {
        __syncthreads();
        const int cur = (it & 1) * 4096;
        if (it + 1 < niter) {
            const int nxt = ((it + 1) & 1) * 4096;
            const int ko = (it + 1) * 64;
            gll16(gA + ko,      As + nxt + (w * 2 + 0) * 512);
            gll16(gA + ko + 32, As + nxt + (w * 2 + 1) * 512);
            gll16(gB + ko,      Bs + nxt + (w * 2 + 0) * 512);
            gll16(gB + ko + 32, Bs + nxt + (w * 2 + 1) * 512);
        }
        #pragma unroll
        for (int ks = 0; ks < 2; ++ks) {
            short8 af[2], bf[2];
            #pragma unroll
            for (int i = 0; i < 2; ++i)
                af[i] = *(const short8*)(As + cur + ((wm * 2 + i) * 2 + ks) * 512 + lane * 8);
            #pragma unroll
            for (int j = 0; j < 2; ++j)
                bf[j] = *(const short8*)(Bs + cur + ((wn * 2 + j) * 2 + ks) * 512 + lane * 8);
            #pragma unroll
            for (int i = 0; i < 2; ++i)
                #pragma unroll
                for (int j = 0; j < 2; ++j)
                    acc[i][j] = __builtin_amdgcn_mfma_f32_16x16x32_bf16(
                        af[i], bf[j], acc[i][j], 0, 0, 0);
        }
    }

    const int quad = lane >> 4, m16 = lane & 15;
    #pragma unroll
    for (int i = 0; i < 2; ++i)
        #pragma unroll
        for (int j = 0; j < 2; ++j) {
            const int col = colBase + wn * 32 + j * 16 + m16;
            #pragma unroll
            for (int r = 0; r < 4; ++r) {
                const int row = rowBase + wm * 32 + i * 16 + quad * 4 + r;
                if (OUT_BF16)
                    ((ushort*)Cv)[(size_t)row * N + col] = f2bf(acc[i][j][r]);
                else
                    ((float*)Cv)[(size_t)row * N + col] = acc[i][j][r];
            }
        }
}

// ---------------------------------------------------------------------------
// paths+phi body (R10-identical)
// ---------------------------------------------------------------------------
__device__ __forceinline__ void phi_body(
    const ushort* __restrict__ xb, const ushort* __restrict__ Wpt,
    const float* __restrict__ bp, ushort* __restrict__ Phi,
    int blk, float* red, float* p_s)
{
    const int tid = threadIdx.x;
    const int lane = tid & 63, w = tid >> 6;
    const int quad = lane >> 4, m16 = lane & 15;
    const int row0 = blk * 16;

    f32x4 acc[5];
    #pragma unroll
    for (int nb = 0; nb < 5; ++nb) acc[nb] = (f32x4)0.0f;

    const ushort* ap = xb + (size_t)(row0 + m16) * 1024 + w * 256 + quad * 8;
    const ushort* bpz = Wpt + (size_t)m16 * 1024 + w * 256 + quad * 8;
    #pragma unroll
    for (int it = 0; it < 8; ++it) {
        const short8 af = *(const short8*)(ap + it * 32);
        #pragma unroll
        for (int nb = 0; nb < 5; ++nb) {
            const short8 bf = *(const short8*)(bpz + (size_t)nb * 16 * 1024 + it * 32);
            acc[nb] = __builtin_amdgcn_mfma_f32_16x16x32_bf16(af, bf, acc[nb], 0, 0, 0);
        }
    }
    #pragma unroll
    for (int nb = 0; nb < 5; ++nb)
        #pragma unroll
        for (int r = 0; r < 4; ++r)
            red[(w * 16 + quad * 4 + r) * 80 + nb * 16 + m16] = acc[nb][r];
    __syncthreads();
    #pragma unroll
    for (int j = 0; j < 5; ++j) {
        const int i = tid + j * 256;
        const int rr = i / 80, cc = i - rr * 80;
        const float v = red[(0 * 16 + rr) * 80 + cc] + red[(1 * 16 + rr) * 80 + cc] +
                        red[(2 * 16 + rr) * 80 + cc] + red[(3 * 16 + rr) * 80 + cc] + bp[cc];
        p_s[rr * 80 + cc] = 1.0f / (1.0f + __expf(-v));
    }
    __syncthreads();
    #pragma unroll
    for (int j = 0; j < 8; ++j) {
        const int c = tid + j * 256;
        const int rr = c >> 7, rem = c & 127;
        const int h = rem >> 3, f8 = (rem & 7) * 8;
        const float* pr = &p_s[rr * 80 + h * 5];
        ushort o[8];
        #pragma unroll
        for (int e = 0; e < 8; ++e) {
            const int f = f8 + e;
            float val = 0.0f;
            if (f < 62) {
                int d, off;
                if (f < 2)       { d = 1; off = 0; }
                else if (f < 6)  { d = 2; off = 2; }
                else if (f < 14) { d = 3; off = 6; }
                else if (f < 30) { d = 4; off = 14; }
                else             { d = 5; off = 30; }
                const int e2 = f - off;
                float prod = 1.0f;
                for (int jj = 1; jj <= d; ++jj) {
                    const float p = pr[jj - 1];
                    prod *= ((e2 >> (d - jj)) & 1) ? (1.0f - p) : p;
                }
                val = prod;
            }
            o[e] = f2bf(val);
        }
        const int grow = row0 + rr;
        const int b = grow >> 10, t = grow & 1023;
        *(uint4*)(Phi + ((size_t)(b * 16 + h) * 1024 + t) * 64 + f8) =
            *(const uint4*)o;
    }
}

// ---------------------------------------------------------------------------
// mid: blocks [0,128) = paths+phi FIRST (overlaps the GEMM),
//      blocks [128,640) = Vt GEMM (Wvt @ xb^T), 64x64 tiles.  (R10-identical)
// ---------------------------------------------------------------------------
__global__ __launch_bounds__(256) void mid_kernel(
    const ushort* __restrict__ xb, const ushort* __restrict__ Wvt,
    const ushort* __restrict__ Wpt, const float* __restrict__ bp,
    ushort* __restrict__ Vt, ushort* __restrict__ Phi)
{
    __shared__ __align__(16) char sm[32768];
    const int bid = blockIdx.x;
    if (bid < 128) {
        float* red = (float*)sm;             // 20480 B
        float* p_s = (float*)(sm + 20480);   // 5120 B
        phi_body(xb, Wpt, bp, Phi, bid, red, p_s);
    } else {
        const int g = bid - 128;
        ushort* As = (ushort*)sm;           // 2 x 4096 ushorts
        ushort* Bs = As + 8192;             // 2 x 4096 ushorts
        gemm_body<true>(Wvt, xb, Vt, 2048, 1024,
                        g & 31, g >> 5, As, Bs);
    }
}

// ---------------------------------------------------------------------------
// final GEMM: out = ctxb @ Wot^T  (fp32 out). grid (16, 32).  (R10-identical)
// ---------------------------------------------------------------------------
__global__ __launch_bounds__(256) void gemm_out(
    const ushort* __restrict__ ctxb, const ushort* __restrict__ Wot,
    float* __restrict__ out)
{
    __shared__ __align__(16) ushort sm[16384];
    gemm_body<false>(ctxb, Wot, out, 1024, 1024,
                     blockIdx.x, blockIdx.y, sm, sm + 8192);
}

// ---------------------------------------------------------------------------
// MFMA attention, S^T form. NEW: CU-pair-balanced qt mapping —
// qt = (by & 16) ? bx : 15-bx, so co-resident blocks i and i+256 (same bx,
// by differing by 16) carry complementary qt (sum 15) -> every CU sees
// ~17 k-tiles instead of worst-case 34. Each (qt, bh) still occurs once.
// ---------------------------------------------------------------------------
__global__ __launch_bounds__(256) void attn_mfma(
    const ushort* __restrict__ Phi, const ushort* __restrict__ Vt,
    ushort* __restrict__ ctxb)
{
    const int bx = blockIdx.x, by = blockIdx.y;
    const int qt = (by & 16) ? bx : 15 - bx;
    const int bh = by;
    const int b = bh >> 4, h = bh & 15;
    const int tid = threadIdx.x;
    const int lane = tid & 63;
    const int w = tid >> 6;
    const int quad = lane >> 4, m16 = lane & 15;

    __shared__ __align__(16) ushort K_s[2][4096];
    __shared__ __align__(16) ushort V_s[2][4096];
    __shared__ __align__(16) ushort W_s[4096];
    __shared__ float den_s[4][16];

    const int srow = lane & 15;
    const int sk = (lane >> 4) * 8;
    const ushort* gK = Phi + (size_t)bh * 1024 * 64 + (w * 16 + srow) * 64 + sk;
    const ushort* gV = Vt + (size_t)(h * 64 + w * 16 + srow) * 2048 + b * 1024 + sk;

    const int qglob = qt * 64 + w * 16 + m16;
    const ushort* qbase = Phi + ((size_t)bh * 1024 + qglob) * 64 + quad * 8;
    const short8 qf0 = *(const short8*)qbase;
    const short8 qf1 = *(const short8*)(qbase + 32);

    f32x4 cacc[4];
    #pragma unroll
    for (int nb = 0; nb < 4; ++nb) cacc[nb] = (f32x4)0.0f;
    float den = 0.0f;

    gll16(gK,      K_s[0] + (w * 2 + 0) * 512);
    gll16(gK + 32, K_s[0] + (w * 2 + 1) * 512);
    gll16(gV,      V_s[0] + (w * 2 + 0) * 512);
    gll16(gV + 32, V_s[0] + (w * 2 + 1) * 512);

    const float C = 0.28853901817f;   // 0.2 * log2(e)

    for (int kt = 0; kt <= qt; ++kt) {
        const int cur = kt & 1;
        __syncthreads();
        if (kt < qt) {
            const int nxt = cur ^ 1;
            const ushort* nK = gK + (kt + 1) * 4096;
            const ushort* nV = gV + (kt + 1) * 64;
            gll16(nK,      K_s[nxt] + (w * 2 + 0) * 512);
            gll16(nK + 32, K_s[nxt] + (w * 2 + 1) * 512);
            gll16(nV,      V_s[nxt] + (w * 2 + 0) * 512);
            gll16(nV + 32, V_s[nxt] + (w * 2 + 1) * 512);
        }
        const bool diag = (kt == qt);
        #pragma unroll
        for (int nb = 0; nb < 4; ++nb) {
            const short8 kf0 = *(const short8*)(K_s[cur] + (nb * 2 + 0) * 512 + lane * 8);
            const short8 kf1 = *(const short8*)(K_s[cur] + (nb * 2 + 1) * 512 + lane * 8);
            f32x4 s = (f32x4)0.0f;
            s = __builtin_amdgcn_mfma_f32_16x16x32_bf16(kf0, qf0, s, 0, 0, 0);
            s = __builtin_amdgcn_mfma_f32_16x16x32_bf16(kf1, qf1, s, 0, 0, 0);
            ushort o[4];
            if (diag) {
                const int k0g = kt * 64 + nb * 16 + quad * 4;
                #pragma unroll
                for (int r = 0; r < 4; ++r) {
                    float wgt = 0.0f;
                    if (k0g + r <= qglob) wgt = exp2f(s[r] * C);
                    den += wgt;
                    o[r] = f2bf(wgt);
                }
            } else {
                #pragma unroll
                for (int r = 0; r < 4; ++r) {
                    const float wgt = exp2f(s[r] * C);
                    den += wgt;
                    o[r] = f2bf(wgt);
                }
            }
            const int addr = (w * 2 + (nb >> 1)) * 512 +
                             ((nb & 1) * 2 + (quad >> 1)) * 128 +
                             m16 * 8 + (quad & 1) * 4;
            *(uint2*)(W_s + addr) = *(const uint2*)o;
        }
        const short8 wf0 = *(const short8*)(W_s + (w * 2 + 0) * 512 + lane * 8);
        const short8 wf1 = *(const short8*)(W_s + (w * 2 + 1) * 512 + lane * 8);
        #pragma unroll
        for (int nb = 0; nb < 4; ++nb) {
            const short8 vf0 = *(const short8*)(V_s[cur] + (nb * 2 + 0) * 512 + lane * 8);
            const short8 vf1 = *(const short8*)(V_s[cur] + (nb * 2 + 1) * 512 + lane * 8);
            cacc[nb] = __builtin_amdgcn_mfma_f32_16x16x32_bf16(wf0, vf0, cacc[nb], 0, 0, 0);
            cacc[nb] = __builtin_amdgcn_mfma_f32_16x16x32_bf16(wf1, vf1, cacc[nb], 0, 0, 0);
        }
    }

    den += __shfl_xor(den, 16);
    den += __shfl_xor(den, 32);
    den_s[w][m16] = den;
    __syncthreads();
    float inv[4];
    #pragma unroll
    for (int r = 0; r < 4; ++r) inv[r] = 1.0f / den_s[w][quad * 4 + r];

    #pragma unroll
    for (int nb = 0; nb < 4; ++nb) {
        const int dim = h * 64 + nb * 16 + m16;
        #pragma unroll
        for (int r = 0; r < 4; ++r) {
            const int token = qt * 64 + w * 16 + quad * 4 + r;
            ctxb[(size_t)(b * 1024 + token) * D_MODEL + dim] = f2bf(cacc[nb][r] * inv[r]);
        }
    }
}

// ---------------------------------------------------------------------------
extern "C" void kernel_launch(void* const* d_in, const int* in_sizes, int n_in,
                              void* d_out, int out_size, void* d_ws, size_t ws_size,
                              hipStream_t stream)
{
    const float* x  = (const float*)d_in[0];
    const float* Wp = (const float*)d_in[1];
    const float* bp = (const float*)d_in[2];
    const float* Wv = (const float*)d_in[3];
    const float* Wo = (const float*)d_in[4];
    float* out = (float*)d_out;

    char* ws = (char*)d_ws;
    ushort* xb   = (ushort*)(ws);                 // 4 MB
    ushort* Wvt  = (ushort*)(ws + (4u  << 20));   // 2 MB
    ushort* Wot  = (ushort*)(ws + (6u  << 20));   // 2 MB
    ushort* Phi  = (ushort*)(ws + (8u  << 20));   // 4 MB
    ushort* Vt   = (ushort*)(ws + (12u << 20));   // 4 MB
    ushort* ctxb = (ushort*)(ws + (16u << 20));   // 4 MB
    ushort* Wpt  = (ushort*)(ws + (20u << 20));   // 160 KB

    prologue<<<3088, 256, 0, stream>>>(x, Wv, Wo, Wp, xb, Wvt, Wot, Wpt);
    mid_kernel<<<640, 256, 0, stream>>>(xb, Wvt, Wpt, bp, Vt, Phi);
    attn_mfma<<<dim3(16, 32), 256, 0, stream>>>(Phi, Vt, ctxb);
    gemm_out<<<dim3(16, 32), 256, 0, stream>>>(ctxb, Wot, out);
}

// Round 13
// 141.662 us; speedup vs baseline: 1.0339x; 1.0022x over previous
//
#include <hip/hip_runtime.h>
#include <hip/hip_bf16.h>

#define B_SZ 2
#define T_SEQ 1024
#define D_MODEL 1024
#define N_HEADS 16
#define TREE_DEPTH 5
#define DH 64

typedef __attribute__((ext_vector_type(8))) short short8;
typedef __attribute__((ext_vector_type(4))) float f32x4;

__device__ __forceinline__ ushort f2bf(float f) {
    uint32_t u = __float_as_uint(f);
    u += 0x7FFFu + ((u >> 16) & 1u);
    return (ushort)(u >> 16);
}

// async global->LDS 16B/lane; dest = wave-uniform base + lane*16
__device__ __forceinline__ void gll16(const void* g, void* l) {
    __builtin_amdgcn_global_load_lds(
        (const __attribute__((address_space(1))) void*)g,
        (__attribute__((address_space(3))) void*)l, 16, 0, 0);
}

// ---------------------------------------------------------------------------
// Fused prologue: [0,1024) convert x->xb ; [1024,3072) transpose Wv/Wo ;
// [3072,3088) transpose Wp.   (R12-identical)
// ---------------------------------------------------------------------------
__global__ __launch_bounds__(256) void prologue(
    const float* __restrict__ x, const float* __restrict__ Wv,
    const float* __restrict__ Wo, const float* __restrict__ Wp,
    ushort* __restrict__ xb, ushort* __restrict__ Wvt,
    ushort* __restrict__ Wot, ushort* __restrict__ Wpt)
{
    __shared__ __align__(16) char sm[20480];
    const int bid = blockIdx.x, tid = threadIdx.x;
    if (bid < 1024) {
        const int i = (bid * 256 + tid) * 8;
        const float4 a = *(const float4*)(x + i);
        const float4 b = *(const float4*)(x + i + 4);
        ushort o[8] = {f2bf(a.x), f2bf(a.y), f2bf(a.z), f2bf(a.w),
                       f2bf(b.x), f2bf(b.y), f2bf(b.z), f2bf(b.w)};
        *(uint4*)(xb + i) = *(const uint4*)o;
    } else if (bid < 3072) {
        const int t = bid - 1024;
        const float* W = (t < 1024) ? Wv : Wo;
        ushort* Wt = (t < 1024) ? Wvt : Wot;
        const int ti = t & 1023;
        const int n0 = (ti & 31) * 32, k0 = (ti >> 5) * 32;
        float (*tile)[33] = (float(*)[33])sm;
        const int tx = tid & 31, ty = tid >> 5;
        #pragma unroll
        for (int i = 0; i < 4; ++i)
            tile[ty + i * 8][tx] = W[(size_t)(k0 + ty + i * 8) * 1024 + n0 + tx];
        __syncthreads();
        #pragma unroll
        for (int i = 0; i < 4; ++i)
            Wt[(size_t)(n0 + ty + i * 8) * 1024 + k0 + tx] = f2bf(tile[tx][ty + i * 8]);
    } else {
        float* tile = (float*)sm;            // 64*80
        const int k0 = (bid - 3072) * 64;
        #pragma unroll
        for (int j = 0; j < 20; ++j) {
            const int i = tid + j * 256;     // i = k*80 + n
            tile[i] = Wp[(size_t)k0 * 80 + i];
        }
        __syncthreads();
        #pragma unroll
        for (int j = 0; j < 20; ++j) {
            const int o = tid + j * 256;     // o = n*64 + k
            const int n = o >> 6, k = o & 63;
            Wpt[(size_t)n * 1024 + k0 + k] = f2bf(tile[k * 80 + n]);
        }
    }
}

// ---------------------------------------------------------------------------
// bf16 MFMA GEMM body: C(MxN) = A(MxK) @ Bt(NxK)^T. BM=64 BN=64 BK=128,
// 4 waves (2x2). Both operands double-buffered gll16; HALF the barriers of
// BK=64 (8 iters for K=1024). LDS 64 KB -> 2 blocks/CU (grid-capped anyway).
// Sub-block layout: (rowblock rb 0..3)*4 + kseg 0..3, each 512 ushorts.
// ---------------------------------------------------------------------------
template <bool OUT_BF16>
__device__ __forceinline__ void gemm_body(
    const ushort* __restrict__ A, const ushort* __restrict__ Bt,
    void* __restrict__ Cv, int N, int K, int bx, int by,
    ushort* As, ushort* Bs)
{
    const int tid = threadIdx.x;
    const int lane = tid & 63;
    const int w = tid >> 6;
    const int wm = w & 1, wn = w >> 1;
    const int rowBase = by * 64;
    const int colBase = bx * 64;

    const int srow = lane & 15;
    const int sk = (lane >> 4) * 8;

    const ushort* gA = A + (size_t)(rowBase + w * 16 + srow) * K + sk;
    const ushort* gB = Bt + (size_t)(colBase + w * 16 + srow) * K + sk;

    f32x4 acc[2][2];
    #pragma unroll
    for (int i = 0; i < 2; ++i) {
        acc[i][0] = (f32x4)0.0f;
        acc[i][1] = (f32x4)0.0f;
    }

    // preload tile 0 (4 k-segments of 32 each, per operand, per wave)
    #pragma unroll
    for (int ks = 0; ks < 4; ++ks) {
        gll16(gA + ks * 32, As + (w * 4 + ks) * 512);
        gll16(gB + ks * 32, Bs + (w * 4 + ks) * 512);
    }

    const int niter = K / 128;
    for (int it = 0; it < niter; ++it) {
        __syncthreads();
        const int cur = (it & 1) * 8192;
        if (it + 1 < niter) {
            const int nxt = ((it + 1) & 1) * 8192;
            const int ko = (it + 1) * 128;
            #pragma unroll
            for (int ks = 0; ks < 4; ++ks) {
                gll16(gA + ko + ks * 32, As + nxt + (w * 4 + ks) * 512);
                gll16(gB + ko + ks * 32, Bs + nxt + (w * 4 + ks) * 512);
            }
        }
        #pragma unroll
        for (int ks = 0; ks < 4; ++ks) {
            short8 af[2], bf[2];
            #pragma unroll
            for (int i = 0; i < 2; ++i)
                af[i] = *(const short8*)(As + cur + ((wm * 2 + i) * 4 + ks) * 512 + lane * 8);
            #pragma unroll
            for (int j = 0; j < 2; ++j)
                bf[j] = *(const short8*)(Bs + cur + ((wn * 2 + j) * 4 + ks) * 512 + lane * 8);
            #pragma unroll
            for (int i = 0; i < 2; ++i)
                #pragma unroll
                for (int j = 0; j < 2; ++j)
                    acc[i][j] = __builtin_amdgcn_mfma_f32_16x16x32_bf16(
                        af[i], bf[j], acc[i][j], 0, 0, 0);
        }
    }

    const int quad = lane >> 4, m16 = lane & 15;
    #pragma unroll
    for (int i = 0; i < 2; ++i)
        #pragma unroll
        for (int j = 0; j < 2; ++j) {
            const int col = colBase + wn * 32 + j * 16 + m16;
            #pragma unroll
            for (int r = 0; r < 4; ++r) {
                const int row = rowBase + wm * 32 + i * 16 + quad * 4 + r;
                if (OUT_BF16)
                    ((ushort*)Cv)[(size_t)row * N + col] = f2bf(acc[i][j][r]);
                else
                    ((float*)Cv)[(size_t)row * N + col] = acc[i][j][r];
            }
        }
}

// ---------------------------------------------------------------------------
// paths+phi body (R12-identical)
// ---------------------------------------------------------------------------
__device__ __forceinline__ void phi_body(
    const ushort* __restrict__ xb, const ushort* __restrict__ Wpt,
    const float* __restrict__ bp, ushort* __restrict__ Phi,
    int blk, float* red, float* p_s)
{
    const int tid = threadIdx.x;
    const int lane = tid & 63, w = tid >> 6;
    const int quad = lane >> 4, m16 = lane & 15;
    const int row0 = blk * 16;

    f32x4 acc[5];
    #pragma unroll
    for (int nb = 0; nb < 5; ++nb) acc[nb] = (f32x4)0.0f;

    const ushort* ap = xb + (size_t)(row0 + m16) * 1024 + w * 256 + quad * 8;
    const ushort* bpz = Wpt + (size_t)m16 * 1024 + w * 256 + quad * 8;
    #pragma unroll
    for (int it = 0; it < 8; ++it) {
        const short8 af = *(const short8*)(ap + it * 32);
        #pragma unroll
        for (int nb = 0; nb < 5; ++nb) {
            const short8 bf = *(const short8*)(bpz + (size_t)nb * 16 * 1024 + it * 32);
            acc[nb] = __builtin_amdgcn_mfma_f32_16x16x32_bf16(af, bf, acc[nb], 0, 0, 0);
        }
    }
    #pragma unroll
    for (int nb = 0; nb < 5; ++nb)
        #pragma unroll
        for (int r = 0; r < 4; ++r)
            red[(w * 16 + quad * 4 + r) * 80 + nb * 16 + m16] = acc[nb][r];
    __syncthreads();
    #pragma unroll
    for (int j = 0; j < 5; ++j) {
        const int i = tid + j * 256;
        const int rr = i / 80, cc = i - rr * 80;
        const float v = red[(0 * 16 + rr) * 80 + cc] + red[(1 * 16 + rr) * 80 + cc] +
                        red[(2 * 16 + rr) * 80 + cc] + red[(3 * 16 + rr) * 80 + cc] + bp[cc];
        p_s[rr * 80 + cc] = 1.0f / (1.0f + __expf(-v));
    }
    __syncthreads();
    #pragma unroll
    for (int j = 0; j < 8; ++j) {
        const int c = tid + j * 256;
        const int rr = c >> 7, rem = c & 127;
        const int h = rem >> 3, f8 = (rem & 7) * 8;
        const float* pr = &p_s[rr * 80 + h * 5];
        ushort o[8];
        #pragma unroll
        for (int e = 0; e < 8; ++e) {
            const int f = f8 + e;
            float val = 0.0f;
            if (f < 62) {
                int d, off;
                if (f < 2)       { d = 1; off = 0; }
                else if (f < 6)  { d = 2; off = 2; }
                else if (f < 14) { d = 3; off = 6; }
                else if (f < 30) { d = 4; off = 14; }
                else             { d = 5; off = 30; }
                const int e2 = f - off;
                float prod = 1.0f;
                for (int jj = 1; jj <= d; ++jj) {
                    const float p = pr[jj - 1];
                    prod *= ((e2 >> (d - jj)) & 1) ? (1.0f - p) : p;
                }
                val = prod;
            }
            o[e] = f2bf(val);
        }
        const int grow = row0 + rr;
        const int b = grow >> 10, t = grow & 1023;
        *(uint4*)(Phi + ((size_t)(b * 16 + h) * 1024 + t) * 64 + f8) =
            *(const uint4*)o;
    }
}

// ---------------------------------------------------------------------------
// mid: blocks [0,128) = paths+phi FIRST (overlaps the GEMM),
//      blocks [128,640) = Vt GEMM (Wvt @ xb^T), 64x64 tiles, BK=128.
// ---------------------------------------------------------------------------
__global__ __launch_bounds__(256) void mid_kernel(
    const ushort* __restrict__ xb, const ushort* __restrict__ Wvt,
    const ushort* __restrict__ Wpt, const float* __restrict__ bp,
    ushort* __restrict__ Vt, ushort* __restrict__ Phi)
{
    __shared__ __align__(16) char sm[65536];
    const int bid = blockIdx.x;
    if (bid < 128) {
        float* red = (float*)sm;             // 20480 B
        float* p_s = (float*)(sm + 20480);   // 5120 B
        phi_body(xb, Wpt, bp, Phi, bid, red, p_s);
    } else {
        const int g = bid - 128;
        ushort* As = (ushort*)sm;           // 2 x 8192 ushorts (32 KB)
        ushort* Bs = As + 16384;            // 2 x 8192 ushorts (32 KB)
        gemm_body<true>(Wvt, xb, Vt, 2048, 1024,
                        g & 31, g >> 5, As, Bs);
    }
}

// ---------------------------------------------------------------------------
// final GEMM: out = ctxb @ Wot^T  (fp32 out). grid (16, 32).
// ---------------------------------------------------------------------------
__global__ __launch_bounds__(256) void gemm_out(
    const ushort* __restrict__ ctxb, const ushort* __restrict__ Wot,
    float* __restrict__ out)
{
    __shared__ __align__(16) ushort sm[32768];   // As 2x8192 + Bs 2x8192
    gemm_body<false>(ctxb, Wot, out, 1024, 1024,
                     blockIdx.x, blockIdx.y, sm, sm + 16384);
}

// ---------------------------------------------------------------------------
// MFMA attention, S^T form, CU-pair-balanced qt mapping (R12-identical).
// ---------------------------------------------------------------------------
__global__ __launch_bounds__(256) void attn_mfma(
    const ushort* __restrict__ Phi, const ushort* __restrict__ Vt,
    ushort* __restrict__ ctxb)
{
    const int bx = blockIdx.x, by = blockIdx.y;
    const int qt = (by & 16) ? bx : 15 - bx;
    const int bh = by;
    const int b = bh >> 4, h = bh & 15;
    const int tid = threadIdx.x;
    const int lane = tid & 63;
    const int w = tid >> 6;
    const int quad = lane >> 4, m16 = lane & 15;

    __shared__ __align__(16) ushort K_s[2][4096];
    __shared__ __align__(16) ushort V_s[2][4096];
    __shared__ __align__(16) ushort W_s[4096];
    __shared__ float den_s[4][16];

    const int srow = lane & 15;
    const int sk = (lane >> 4) * 8;
    const ushort* gK = Phi + (size_t)bh * 1024 * 64 + (w * 16 + srow) * 64 + sk;
    const ushort* gV = Vt + (size_t)(h * 64 + w * 16 + srow) * 2048 + b * 1024 + sk;

    const int qglob = qt * 64 + w * 16 + m16;
    const ushort* qbase = Phi + ((size_t)bh * 1024 + qglob) * 64 + quad * 8;
    const short8 qf0 = *(const short8*)qbase;
    const short8 qf1 = *(const short8*)(qbase + 32);

    f32x4 cacc[4];
    #pragma unroll
    for (int nb = 0; nb < 4; ++nb) cacc[nb] = (f32x4)0.0f;
    float den = 0.0f;

    gll16(gK,      K_s[0] + (w * 2 + 0) * 512);
    gll16(gK + 32, K_s[0] + (w * 2 + 1) * 512);
    gll16(gV,      V_s[0] + (w * 2 + 0) * 512);
    gll16(gV + 32, V_s[0] + (w * 2 + 1) * 512);

    const float C = 0.28853901817f;   // 0.2 * log2(e)

    for (int kt = 0; kt <= qt; ++kt) {
        const int cur = kt & 1;
        __syncthreads();
        if (kt < qt) {
            const int nxt = cur ^ 1;
            const ushort* nK = gK + (kt + 1) * 4096;
            const ushort* nV = gV + (kt + 1) * 64;
            gll16(nK,      K_s[nxt] + (w * 2 + 0) * 512);
            gll16(nK + 32, K_s[nxt] + (w * 2 + 1) * 512);
            gll16(nV,      V_s[nxt] + (w * 2 + 0) * 512);
            gll16(nV + 32, V_s[nxt] + (w * 2 + 1) * 512);
        }
        const bool diag = (kt == qt);
        #pragma unroll
        for (int nb = 0; nb < 4; ++nb) {
            const short8 kf0 = *(const short8*)(K_s[cur] + (nb * 2 + 0) * 512 + lane * 8);
            const short8 kf1 = *(const short8*)(K_s[cur] + (nb * 2 + 1) * 512 + lane * 8);
            f32x4 s = (f32x4)0.0f;
            s = __builtin_amdgcn_mfma_f32_16x16x32_bf16(kf0, qf0, s, 0, 0, 0);
            s = __builtin_amdgcn_mfma_f32_16x16x32_bf16(kf1, qf1, s, 0, 0, 0);
            ushort o[4];
            if (diag) {
                const int k0g = kt * 64 + nb * 16 + quad * 4;
                #pragma unroll
                for (int r = 0; r < 4; ++r) {
                    float wgt = 0.0f;
                    if (k0g + r <= qglob) wgt = exp2f(s[r] * C);
                    den += wgt;
                    o[r] = f2bf(wgt);
                }
            } else {
                #pragma unroll
                for (int r = 0; r < 4; ++r) {
                    const float wgt = exp2f(s[r] * C);
                    den += wgt;
                    o[r] = f2bf(wgt);
                }
            }
            const int addr = (w * 2 + (nb >> 1)) * 512 +
                             ((nb & 1) * 2 + (quad >> 1)) * 128 +
                             m16 * 8 + (quad & 1) * 4;
            *(uint2*)(W_s + addr) = *(const uint2*)o;
        }
        const short8 wf0 = *(const short8*)(W_s + (w * 2 + 0) * 512 + lane * 8);
        const short8 wf1 = *(const short8*)(W_s + (w * 2 + 1) * 512 + lane * 8);
        #pragma unroll
        for (int nb = 0; nb < 4; ++nb) {
            const short8 vf0 = *(const short8*)(V_s[cur] + (nb * 2 + 0) * 512 + lane * 8);
            const short8 vf1 = *(const short8*)(V_s[cur] + (nb * 2 + 1) * 512 + lane * 8);
            cacc[nb] = __builtin_amdgcn_mfma_f32_16x16x32_bf16(wf0, vf0, cacc[nb], 0, 0, 0);
            cacc[nb] = __builtin_amdgcn_mfma_f32_16x16x32_bf16(wf1, vf1, cacc[nb], 0, 0, 0);
        }
    }

    den += __shfl_xor(den, 16);
    den += __shfl_xor(den, 32);
    den_s[w][m16] = den;
    __syncthreads();
    float inv[4];
    #pragma unroll
    for (int r = 0; r < 4; ++r) inv[r] = 1.0f / den_s[w][quad * 4 + r];

    #pragma unroll
    for (int nb = 0; nb < 4; ++nb) {
        const int dim = h * 64 + nb * 16 + m16;
        #pragma unroll
        for (int r = 0; r < 4; ++r) {
            const int token = qt * 64 + w * 16 + quad * 4 + r;
            ctxb[(size_t)(b * 1024 + token) * D_MODEL + dim] = f2bf(cacc[nb][r] * inv[r]);
        }
    }
}

// ---------------------------------------------------------------------------
extern "C" void kernel_launch(void* const* d_in, const int* in_sizes, int n_in,
                              void* d_out, int out_size, void* d_ws, size_t ws_size,
                              hipStream_t stream)
{
    const float* x  = (const float*)d_in[0];
    const float* Wp = (const float*)d_in[1];
    const float* bp = (const float*)d_in[2];
    const float* Wv = (const float*)d_in[3];
    const float* Wo = (const float*)d_in[4];
    float* out = (float*)d_out;

    char* ws = (char*)d_ws;
    ushort* xb   = (ushort*)(ws);                 // 4 MB
    ushort* Wvt  = (ushort*)(ws + (4u  << 20));   // 2 MB
    ushort* Wot  = (ushort*)(ws + (6u  << 20));   // 2 MB
    ushort* Phi  = (ushort*)(ws + (8u  << 20));   // 4 MB
    ushort* Vt   = (ushort*)(ws + (12u << 20));   // 4 MB
    ushort* ctxb = (ushort*)(ws + (16u << 20));   // 4 MB
    ushort* Wpt  = (ushort*)(ws + (20u << 20));   // 160 KB

    prologue<<<3088, 256, 0, stream>>>(x, Wv, Wo, Wp, xb, Wvt, Wot, Wpt);
    mid_kernel<<<640, 256, 0, stream>>>(xb, Wvt, Wpt, bp, Vt, Phi);
    attn_mfma<<<dim3(16, 32), 256, 0, stream>>>(Phi, Vt, ctxb);
    gemm_out<<<dim3(16, 32), 256, 0, stream>>>(ctxb, Wot, out);
}